// Round 4
// baseline (92.329 us; speedup 1.0000x reference)
//
#include <hip/hip_runtime.h>
#include <hip/hip_cooperative_groups.h>

namespace cg = cooperative_groups;

#define NN 512
#define AA 512
#define BB 32
#define CC 16
#define BC 512            // B*C
#define OUTW 544          // A+B
#define LOG2E 1.44269504088896340736f

constexpr int G_ROWS = 8;
constexpr int G_COLS = 64;
constexpr int G_KSPL = 8;
constexpr int G_KLEN = AA / G_KSPL;  // 64

constexpr int ITILE  = 4;
constexpr int NJC    = 4;
constexpr int JCHUNK = NN / NJC;  // 128

union SMem {
    struct {
        float xsT[AA][G_ROWS];                 // 16 KB
        float red[G_KSPL][G_COLS][G_ROWS + 1]; // 18.4 KB
    } p1;
    float red2[ITILE][16][32];                 // 8 KB
};

// -------- phase 1: M = (x @ T) * log2e; out[:, :A] = x; out[:, A:] = -1
__device__ __forceinline__ void gemm_phase(SMem& sm, int bx, int t,
                                           const float* __restrict__ x,
                                           const float* __restrict__ T,
                                           float* __restrict__ M,
                                           float* __restrict__ out) {
    const int i0 = (bx >> 3) * G_ROWS;
    const int c0 = (bx & 7) * G_COLS;
    const int kq = t >> 6;
    const int c  = t & 63;

    {
        const int r  = t & 7;
        const int k0 = (t >> 3) * 8;
        const float4 v0 = *(const float4*)(x + (size_t)(i0 + r) * AA + k0);
        const float4 v1 = *(const float4*)(x + (size_t)(i0 + r) * AA + k0 + 4);
        sm.p1.xsT[k0 + 0][r] = v0.x; sm.p1.xsT[k0 + 1][r] = v0.y;
        sm.p1.xsT[k0 + 2][r] = v0.z; sm.p1.xsT[k0 + 3][r] = v0.w;
        sm.p1.xsT[k0 + 4][r] = v1.x; sm.p1.xsT[k0 + 5][r] = v1.y;
        sm.p1.xsT[k0 + 6][r] = v1.z; sm.p1.xsT[k0 + 7][r] = v1.w;
    }
    __syncthreads();

    float acc[G_ROWS];
#pragma unroll
    for (int r = 0; r < G_ROWS; ++r) acc[r] = 0.f;

    const float* Tp = T + (size_t)(kq * G_KLEN) * BC + c0 + c;
#pragma unroll 8
    for (int kk = 0; kk < G_KLEN; ++kk) {
        const float tv = Tp[(size_t)kk * BC];
        const int k = kq * G_KLEN + kk;
        const float4 xa = *(const float4*)&sm.p1.xsT[k][0];
        const float4 xb = *(const float4*)&sm.p1.xsT[k][4];
        acc[0] = fmaf(xa.x, tv, acc[0]);
        acc[1] = fmaf(xa.y, tv, acc[1]);
        acc[2] = fmaf(xa.z, tv, acc[2]);
        acc[3] = fmaf(xa.w, tv, acc[3]);
        acc[4] = fmaf(xb.x, tv, acc[4]);
        acc[5] = fmaf(xb.y, tv, acc[5]);
        acc[6] = fmaf(xb.z, tv, acc[6]);
        acc[7] = fmaf(xb.w, tv, acc[7]);
    }

#pragma unroll
    for (int r = 0; r < G_ROWS; ++r) sm.p1.red[kq][c][r] = acc[r];
    __syncthreads();

    {
        const int r  = t >> 6;
        const int cc = t & 63;
        float s = 0.f;
#pragma unroll
        for (int q = 0; q < G_KSPL; ++q) s += sm.p1.red[q][cc][r];
        M[(size_t)(i0 + r) * BC + c0 + cc] = s * LOG2E;
        out[(size_t)(i0 + r) * OUTW + c0 + cc] = x[(size_t)(i0 + r) * AA + c0 + cc];
    }
    if ((bx & 7) == 0 && t < G_ROWS * BB) {
        out[(size_t)(i0 + (t >> 5)) * OUTW + AA + (t & 31)] = -1.0f;
    }
}

// -------- phase 2: out[i, A+b] += sum_{j in chunk jc} exp2(-sum_c |M[i]-M[j]|)
__device__ __forceinline__ void pairwise_phase(SMem& sm, int bx, int t,
                                               const float* __restrict__ M,
                                               float* __restrict__ out) {
    const int i0 = (bx >> 2) * ITILE;
    const int jc = bx & 3;
    const int b  = t & 31;
    const int jg = t >> 5;

    float mi[ITILE][CC];
#pragma unroll
    for (int r = 0; r < ITILE; ++r) {
        const float4* p = (const float4*)(M + (size_t)(i0 + r) * BC + b * CC);
        const float4 v0 = p[0], v1 = p[1], v2 = p[2], v3 = p[3];
        mi[r][0] = v0.x;  mi[r][1] = v0.y;  mi[r][2] = v0.z;  mi[r][3] = v0.w;
        mi[r][4] = v1.x;  mi[r][5] = v1.y;  mi[r][6] = v1.z;  mi[r][7] = v1.w;
        mi[r][8] = v2.x;  mi[r][9] = v2.y;  mi[r][10] = v2.z; mi[r][11] = v2.w;
        mi[r][12] = v3.x; mi[r][13] = v3.y; mi[r][14] = v3.z; mi[r][15] = v3.w;
    }

    float acc[ITILE];
#pragma unroll
    for (int r = 0; r < ITILE; ++r) acc[r] = 0.f;

    const int jbase = jc * JCHUNK + jg * (JCHUNK / 16);
#pragma unroll
    for (int jj = 0; jj < JCHUNK / 16; ++jj) {
        const int j = jbase + jj;
        const float4* p = (const float4*)(M + (size_t)j * BC + b * CC);
        const float4 m0 = p[0], m1 = p[1], m2 = p[2], m3 = p[3];
        float mj[CC] = {m0.x, m0.y, m0.z, m0.w, m1.x, m1.y, m1.z, m1.w,
                        m2.x, m2.y, m2.z, m2.w, m3.x, m3.y, m3.z, m3.w};
#pragma unroll
        for (int r = 0; r < ITILE; ++r) {
            float d0 = 0.f, d1 = 0.f, d2 = 0.f, d3 = 0.f;
#pragma unroll
            for (int c = 0; c < CC; c += 4) {
                d0 += fabsf(mj[c + 0] - mi[r][c + 0]);
                d1 += fabsf(mj[c + 1] - mi[r][c + 1]);
                d2 += fabsf(mj[c + 2] - mi[r][c + 2]);
                d3 += fabsf(mj[c + 3] - mi[r][c + 3]);
            }
            const float d = (d0 + d1) + (d2 + d3);
            acc[r] += __builtin_amdgcn_exp2f(-d);
        }
    }

#pragma unroll
    for (int r = 0; r < ITILE; ++r) sm.red2[r][jg][b] = acc[r];
    __syncthreads();

    if (t < 32 * ITILE) {
        const int b2 = t & 31;
        const int r  = t >> 5;
        float s = 0.f;
#pragma unroll
        for (int g = 0; g < 16; ++g) s += sm.red2[r][g][b2];
        atomicAdd(out + (size_t)(i0 + r) * OUTW + AA + b2, s);
    }
}

__global__ __launch_bounds__(512, 4) void fused_kernel(const float* __restrict__ x,
                                                       const float* __restrict__ T,
                                                       float* __restrict__ M,
                                                       float* __restrict__ out) {
    __shared__ SMem sm;
    const int bx = blockIdx.x;
    const int t  = threadIdx.x;
    gemm_phase(sm, bx, t, x, T, M, out);
    cg::this_grid().sync();
    pairwise_phase(sm, bx, t, M, out);
}

// -------- fallback path (proven round-3 kernels) in case coop launch is rejected
__global__ __launch_bounds__(512) void gemm_kernel(const float* __restrict__ x,
                                                   const float* __restrict__ T,
                                                   float* __restrict__ M,
                                                   float* __restrict__ out) {
    __shared__ SMem sm;
    gemm_phase(sm, blockIdx.x, threadIdx.x, x, T, M, out);
}

__global__ __launch_bounds__(512) void pairwise_kernel(const float* __restrict__ M,
                                                       float* __restrict__ out) {
    __shared__ SMem sm;
    pairwise_phase(sm, blockIdx.x, threadIdx.x, M, out);
}

extern "C" void kernel_launch(void* const* d_in, const int* in_sizes, int n_in,
                              void* d_out, int out_size, void* d_ws, size_t ws_size,
                              hipStream_t stream) {
    const float* x = (const float*)d_in[0];  // (N, A)
    const float* T = (const float*)d_in[1];  // (A, B, C)
    float* out = (float*)d_out;              // (N, A+B)
    float* M   = (float*)d_ws;               // (N, B*C) scratch, 1 MiB

    void* args[] = {(void*)&x, (void*)&T, (void*)&M, (void*)&out};
    hipError_t err = hipLaunchCooperativeKernel((const void*)fused_kernel,
                                                dim3(512), dim3(512), args, 0, stream);
    if (err != hipSuccess) {
        // fallback: two ordinary launches (correct, slightly slower)
        gemm_kernel<<<512, 512, 0, stream>>>(x, T, M, out);
        pairwise_kernel<<<dim3(NN * NJC / ITILE), 512, 0, stream>>>(M, out);
    }
}

// Round 5
// 29.031 us; speedup vs baseline: 3.1803x; 3.1803x over previous
//
#include <hip/hip_runtime.h>

#define NN 512
#define AA 512
#define BB 32
#define CC 16
#define BC 512            // B*C
#define OUTW 544          // A+B
#define LOG2E 1.44269504088896340736f

typedef float f32x4 __attribute__((ext_vector_type(4)));

constexpr int G_ROWS = 8;
constexpr int G_COLS = 64;
constexpr int G_KSPL = 8;
constexpr int G_KLEN = AA / G_KSPL;  // 64

constexpr int ITILE  = 4;
constexpr int NJC    = 4;
constexpr int JCHUNK = NN / NJC;  // 128

// ---------------- gemm: M = (x @ T) * log2e; out[:, :A] = x; out[:, A:] = -1
__global__ __launch_bounds__(512) void gemm_kernel(const float* __restrict__ x,
                                                   const float* __restrict__ T,
                                                   float* __restrict__ M,
                                                   float* __restrict__ out) {
    const int bx = blockIdx.x;
    const int i0 = (bx >> 3) * G_ROWS;
    const int c0 = (bx & 7) * G_COLS;
    const int t  = threadIdx.x;
    const int kq = t >> 6;
    const int c  = t & 63;

    __shared__ float xsT[AA][G_ROWS];                    // 16 KB
    __shared__ float red[G_KSPL][G_COLS][G_ROWS + 1];    // 18.4 KB

    {
        const int r  = t & 7;
        const int k0 = (t >> 3) * 8;
        const float4 v0 = *(const float4*)(x + (size_t)(i0 + r) * AA + k0);
        const float4 v1 = *(const float4*)(x + (size_t)(i0 + r) * AA + k0 + 4);
        xsT[k0 + 0][r] = v0.x; xsT[k0 + 1][r] = v0.y;
        xsT[k0 + 2][r] = v0.z; xsT[k0 + 3][r] = v0.w;
        xsT[k0 + 4][r] = v1.x; xsT[k0 + 5][r] = v1.y;
        xsT[k0 + 6][r] = v1.z; xsT[k0 + 7][r] = v1.w;
    }
    __syncthreads();

    float acc[G_ROWS];
#pragma unroll
    for (int r = 0; r < G_ROWS; ++r) acc[r] = 0.f;

    const float* Tp = T + (size_t)(kq * G_KLEN) * BC + c0 + c;
#pragma unroll 8
    for (int kk = 0; kk < G_KLEN; ++kk) {
        const float tv = Tp[(size_t)kk * BC];
        const int k = kq * G_KLEN + kk;
        const float4 xa = *(const float4*)&xsT[k][0];
        const float4 xb = *(const float4*)&xsT[k][4];
        acc[0] = fmaf(xa.x, tv, acc[0]);
        acc[1] = fmaf(xa.y, tv, acc[1]);
        acc[2] = fmaf(xa.z, tv, acc[2]);
        acc[3] = fmaf(xa.w, tv, acc[3]);
        acc[4] = fmaf(xb.x, tv, acc[4]);
        acc[5] = fmaf(xb.y, tv, acc[5]);
        acc[6] = fmaf(xb.z, tv, acc[6]);
        acc[7] = fmaf(xb.w, tv, acc[7]);
    }

#pragma unroll
    for (int r = 0; r < G_ROWS; ++r) red[kq][c][r] = acc[r];
    __syncthreads();

    {
        const int r  = t >> 6;
        const int cc = t & 63;
        float s = 0.f;
#pragma unroll
        for (int q = 0; q < G_KSPL; ++q) s += red[q][cc][r];
        M[(size_t)(i0 + r) * BC + c0 + cc] = s * LOG2E;  // pre-scale for exp2
        out[(size_t)(i0 + r) * OUTW + c0 + cc] = x[(size_t)(i0 + r) * AA + c0 + cc];
    }
    if ((bx & 7) == 0 && t < G_ROWS * BB) {
        out[(size_t)(i0 + (t >> 5)) * OUTW + AA + (t & 31)] = -1.0f;
    }
}

// ---------------- pairwise: out[i, A+b] += sum_{j in chunk} exp2(-sum_c |M[i]-M[j]|)
// inner loop in float4 vector form: sub + max(t,-t) + add lower to VOP3P pk ops
__global__ __launch_bounds__(512) void pairwise_kernel(const float* __restrict__ M,
                                                       float* __restrict__ out) {
    const int i0 = blockIdx.x * ITILE;
    const int jc = blockIdx.y;
    const int t  = threadIdx.x;
    const int b  = t & 31;   // feature block 0..31
    const int jg = t >> 5;   // j group 0..15

    f32x4 mi[ITILE][4];
#pragma unroll
    for (int r = 0; r < ITILE; ++r) {
        const f32x4* p = (const f32x4*)(M + (size_t)(i0 + r) * BC + b * CC);
#pragma unroll
        for (int q = 0; q < 4; ++q) mi[r][q] = p[q];
    }

    float acc[ITILE];
#pragma unroll
    for (int r = 0; r < ITILE; ++r) acc[r] = 0.f;

    const int jbase = jc * JCHUNK + jg * (JCHUNK / 16);
#pragma unroll
    for (int jj = 0; jj < JCHUNK / 16; ++jj) {   // 8 iterations
        const int j = jbase + jj;
        const f32x4* p = (const f32x4*)(M + (size_t)j * BC + b * CC);
        f32x4 mj[4];
#pragma unroll
        for (int q = 0; q < 4; ++q) mj[q] = p[q];
#pragma unroll
        for (int r = 0; r < ITILE; ++r) {
            f32x4 d4 = {0.f, 0.f, 0.f, 0.f};
#pragma unroll
            for (int q = 0; q < 4; ++q) {
                const f32x4 tdiff = mj[q] - mi[r][q];
                d4 += __builtin_elementwise_max(tdiff, -tdiff);  // pk_max with neg mod
            }
            const float d = (d4.x + d4.y) + (d4.z + d4.w);
            acc[r] += __builtin_amdgcn_exp2f(-d);
        }
    }

    __shared__ float red2[ITILE][16][32];
#pragma unroll
    for (int r = 0; r < ITILE; ++r) red2[r][jg][b] = acc[r];
    __syncthreads();

    if (t < 32 * ITILE) {
        const int b2 = t & 31;
        const int r  = t >> 5;
        float s = 0.f;
#pragma unroll
        for (int g = 0; g < 16; ++g) s += red2[r][g][b2];
        atomicAdd(out + (size_t)(i0 + r) * OUTW + AA + b2, s);
    }
}

extern "C" void kernel_launch(void* const* d_in, const int* in_sizes, int n_in,
                              void* d_out, int out_size, void* d_ws, size_t ws_size,
                              hipStream_t stream) {
    const float* x = (const float*)d_in[0];  // (N, A)
    const float* T = (const float*)d_in[1];  // (A, B, C)
    float* out = (float*)d_out;              // (N, A+B)
    float* M   = (float*)d_ws;               // (N, B*C) scratch, 1 MiB

    gemm_kernel<<<512, 512, 0, stream>>>(x, T, M, out);
    pairwise_kernel<<<dim3(NN / ITILE, NJC), 512, 0, stream>>>(M, out);
}

// Round 6
// 26.496 us; speedup vs baseline: 3.4846x; 1.0957x over previous
//
#include <hip/hip_runtime.h>

#define NN 512
#define AA 512
#define BB 32
#define CC 16
#define BC 512            // B*C
#define OUTW 544          // A+B
#define LOG2E 1.44269504088896340736f

constexpr int G_ROWS = 8;
constexpr int G_COLS = 64;
constexpr int G_KSPL = 8;
constexpr int G_KLEN = AA / G_KSPL;  // 64

constexpr int NT   = 32;   // 512/16 row-tiles
constexpr int TR   = 16;   // tile rows

// ---------------- gemm: M = (x @ T) * log2e; out[:, :A] = x; out[:, A:] = -1
__global__ __launch_bounds__(512) void gemm_kernel(const float* __restrict__ x,
                                                   const float* __restrict__ T,
                                                   float* __restrict__ M,
                                                   float* __restrict__ out) {
    const int bx = blockIdx.x;
    const int i0 = (bx >> 3) * G_ROWS;
    const int c0 = (bx & 7) * G_COLS;
    const int t  = threadIdx.x;
    const int kq = t >> 6;
    const int c  = t & 63;

    __shared__ float xsT[AA][G_ROWS];                    // 16 KB
    __shared__ float red[G_KSPL][G_COLS][G_ROWS + 1];    // 18.4 KB

    {
        const int r  = t & 7;
        const int k0 = (t >> 3) * 8;
        const float4 v0 = *(const float4*)(x + (size_t)(i0 + r) * AA + k0);
        const float4 v1 = *(const float4*)(x + (size_t)(i0 + r) * AA + k0 + 4);
        xsT[k0 + 0][r] = v0.x; xsT[k0 + 1][r] = v0.y;
        xsT[k0 + 2][r] = v0.z; xsT[k0 + 3][r] = v0.w;
        xsT[k0 + 4][r] = v1.x; xsT[k0 + 5][r] = v1.y;
        xsT[k0 + 6][r] = v1.z; xsT[k0 + 7][r] = v1.w;
    }
    __syncthreads();

    float acc[G_ROWS];
#pragma unroll
    for (int r = 0; r < G_ROWS; ++r) acc[r] = 0.f;

    const float* Tp = T + (size_t)(kq * G_KLEN) * BC + c0 + c;
#pragma unroll 8
    for (int kk = 0; kk < G_KLEN; ++kk) {
        const float tv = Tp[(size_t)kk * BC];
        const int k = kq * G_KLEN + kk;
        const float4 xa = *(const float4*)&xsT[k][0];
        const float4 xb = *(const float4*)&xsT[k][4];
        acc[0] = fmaf(xa.x, tv, acc[0]);
        acc[1] = fmaf(xa.y, tv, acc[1]);
        acc[2] = fmaf(xa.z, tv, acc[2]);
        acc[3] = fmaf(xa.w, tv, acc[3]);
        acc[4] = fmaf(xb.x, tv, acc[4]);
        acc[5] = fmaf(xb.y, tv, acc[5]);
        acc[6] = fmaf(xb.z, tv, acc[6]);
        acc[7] = fmaf(xb.w, tv, acc[7]);
    }

#pragma unroll
    for (int r = 0; r < G_ROWS; ++r) red[kq][c][r] = acc[r];
    __syncthreads();

    {
        const int r  = t >> 6;
        const int cc = t & 63;
        float s = 0.f;
#pragma unroll
        for (int q = 0; q < G_KSPL; ++q) s += red[q][cc][r];
        M[(size_t)(i0 + r) * BC + c0 + cc] = s * LOG2E;  // pre-scale for exp2
        out[(size_t)(i0 + r) * OUTW + c0 + cc] = x[(size_t)(i0 + r) * AA + c0 + cc];
    }
    if ((bx & 7) == 0 && t < G_ROWS * BB) {
        out[(size_t)(i0 + (t >> 5)) * OUTW + AA + (t & 31)] = -1.0f;
    }
}

// ---------------- symmetric pairwise over upper-triangle 16x16 row-tile pairs
// block: 512 thr = 32 b x 4 ig x 4 jg; thread: 4 i x 4 j pairs for its b
__global__ __launch_bounds__(512, 4) void pairwise_sym_kernel(const float* __restrict__ M,
                                                              float* __restrict__ out) {
    // decode triangular tile pair (I <= J): row I has NT-I tiles
    int rem = blockIdx.x, I = 0;
    while (rem >= NT - I) { rem -= NT - I; ++I; }
    const int J = I + rem;
    const int i0 = I * TR, j0 = J * TR;
    const bool diag = (I == J);

    const int t  = threadIdx.x;
    const int b  = t & 31;
    const int ig = (t >> 5) & 3;
    const int jg = t >> 7;      // 0..3

    // this thread's 4 i-rows of M[b] into registers (64 VGPRs)
    float mi[4][CC];
#pragma unroll
    for (int p = 0; p < 4; ++p) {
        const float4* src = (const float4*)(M + (size_t)(i0 + ig * 4 + p) * BC + b * CC);
        const float4 v0 = src[0], v1 = src[1], v2 = src[2], v3 = src[3];
        mi[p][0]  = v0.x; mi[p][1]  = v0.y; mi[p][2]  = v0.z; mi[p][3]  = v0.w;
        mi[p][4]  = v1.x; mi[p][5]  = v1.y; mi[p][6]  = v1.z; mi[p][7]  = v1.w;
        mi[p][8]  = v2.x; mi[p][9]  = v2.y; mi[p][10] = v2.z; mi[p][11] = v2.w;
        mi[p][12] = v3.x; mi[p][13] = v3.y; mi[p][14] = v3.z; mi[p][15] = v3.w;
    }

    float accI[4] = {0.f, 0.f, 0.f, 0.f};   // per-i sums over this thread's 4 j
    float accJ[4] = {0.f, 0.f, 0.f, 0.f};   // per-j sums over this thread's 4 i

#pragma unroll
    for (int q = 0; q < 4; ++q) {
        const int j = j0 + jg * 4 + q;
        const float4* src = (const float4*)(M + (size_t)j * BC + b * CC);
        const float4 m0 = src[0], m1 = src[1], m2 = src[2], m3 = src[3];
        const float mj[CC] = {m0.x, m0.y, m0.z, m0.w, m1.x, m1.y, m1.z, m1.w,
                              m2.x, m2.y, m2.z, m2.w, m3.x, m3.y, m3.z, m3.w};
#pragma unroll
        for (int p = 0; p < 4; ++p) {
            float d0 = 0.f, d1 = 0.f, d2 = 0.f, d3 = 0.f;
#pragma unroll
            for (int c = 0; c < CC; c += 4) {
                d0 += fabsf(mj[c + 0] - mi[p][c + 0]);   // v_sub + v_add(abs-mod)
                d1 += fabsf(mj[c + 1] - mi[p][c + 1]);
                d2 += fabsf(mj[c + 2] - mi[p][c + 2]);
                d3 += fabsf(mj[c + 3] - mi[p][c + 3]);
            }
            const float c2 = __builtin_amdgcn_exp2f(-((d0 + d1) + (d2 + d3)));
            accI[p] += c2;
            accJ[q] += c2;
        }
    }

    __shared__ float redI[4][TR][32];   // [jg][i_local][b]
    __shared__ float redJ[4][TR][32];   // [ig][j_local][b]
#pragma unroll
    for (int p = 0; p < 4; ++p) redI[jg][ig * 4 + p][b] = accI[p];
    if (!diag) {
#pragma unroll
        for (int q = 0; q < 4; ++q) redJ[ig][jg * 4 + q][b] = accJ[q];
    }
    __syncthreads();

    const int rl = t >> 5;     // 0..15 local row
    const int b2 = t & 31;
    {
        const float s = redI[0][rl][b2] + redI[1][rl][b2]
                      + redI[2][rl][b2] + redI[3][rl][b2];
        atomicAdd(out + (size_t)(i0 + rl) * OUTW + AA + b2, s);
    }
    if (!diag) {
        const float s = redJ[0][rl][b2] + redJ[1][rl][b2]
                      + redJ[2][rl][b2] + redJ[3][rl][b2];
        atomicAdd(out + (size_t)(j0 + rl) * OUTW + AA + b2, s);
    }
}

extern "C" void kernel_launch(void* const* d_in, const int* in_sizes, int n_in,
                              void* d_out, int out_size, void* d_ws, size_t ws_size,
                              hipStream_t stream) {
    const float* x = (const float*)d_in[0];  // (N, A)
    const float* T = (const float*)d_in[1];  // (A, B, C)
    float* out = (float*)d_out;              // (N, A+B)
    float* M   = (float*)d_ws;               // (N, B*C) scratch, 1 MiB

    gemm_kernel<<<512, 512, 0, stream>>>(x, T, M, out);
    pairwise_sym_kernel<<<NT * (NT + 1) / 2, 512, 0, stream>>>(M, out);
}